// Round 1
// baseline (363.926 us; speedup 1.0000x reference)
//
#include <hip/hip_runtime.h>
#include <math.h>

typedef unsigned short u16;
typedef __bf16 bf16x8 __attribute__((ext_vector_type(8)));
typedef float f32x4 __attribute__((ext_vector_type(4)));
typedef unsigned short u16x8 __attribute__((ext_vector_type(8)));

#define SHIFT 2

static __device__ __forceinline__ f32x4 mfma16(bf16x8 a, bf16x8 b, f32x4 c) {
  return __builtin_amdgcn_mfma_f32_16x16x32_bf16(a, b, c, 0, 0, 0);
}
static __device__ __forceinline__ u16 f2bf(float f) {
  unsigned u = __builtin_bit_cast(unsigned, f);
  unsigned r = u + 0x7fffu + ((u >> 16) & 1u);
  return (u16)(r >> 16);
}

// ---------------- workspace layout (bytes) ----------------
// weights bf16 (transposed to [N][K]):
#define OFF_KVWT  ((size_t)0)                          // 384x192
#define OFF_PRWT  (OFF_KVWT + 384*192*2)               // 192x192
#define OFF_FC1WT (OFF_PRWT + 192*192*2)               // 768x192
#define OFF_FC2WT (OFF_FC1WT + 768*192*2)              // 192x768
#define OFF_SKW   (OFF_FC2WT + 192*768*2)              // 65536x192 bf16
#define OFF_QW    (OFF_SKW + (size_t)65536*192*2)
#define OFF_KVB   (OFF_QW + (size_t)65536*192*2)       // 65536x384 bf16
#define OFF_H1    OFF_SKW                              // aliases skw+qw+kvb (dead by then)
#define OFF_ATTN  (OFF_KVB + (size_t)65536*384*2)      // 65536x192 bf16
#define OFF_Y     (OFF_ATTN + (size_t)65536*192*2)     // 65536x192 f32
#define OFF_HN    (OFF_Y + (size_t)65536*192*4)        // 65536x192 bf16
// total = OFF_HN + 65536*192*2 = 202,137,600 B

// ---------------- K0: weight transpose + f32->bf16 ----------------
__global__ __launch_bounds__(256) void k_prep(
    const float* __restrict__ kv_w, const float* __restrict__ proj_w,
    const float* __restrict__ fc1_w, const float* __restrict__ fc2_w,
    u16* __restrict__ kvT, u16* __restrict__ prT,
    u16* __restrict__ f1T, u16* __restrict__ f2T) {
  int i = blockIdx.x * 256 + threadIdx.x;
  if (i < 192 * 384) kvT[(i % 384) * 192 + i / 384] = f2bf(kv_w[i]);
  if (i < 192 * 192) prT[(i % 192) * 192 + i / 192] = f2bf(proj_w[i]);
  if (i < 192 * 768) f1T[(i % 768) * 192 + i / 768] = f2bf(fc1_w[i]);
  if (i < 768 * 192) f2T[(i % 192) * 768 + i / 192] = f2bf(fc2_w[i]);
}

// ---------------- K1: LN + cyclic shift + window partition ----------------
// one wave per row (4 rows / 256-thr block); q gets *hd^-0.5 folded in
__global__ __launch_bounds__(256) void k_ln_part(
    const float* __restrict__ skip, const float* __restrict__ x_up,
    const float* __restrict__ gam, const float* __restrict__ bet,
    u16* __restrict__ skw, u16* __restrict__ qw) {
  int row = blockIdx.x * 4 + (threadIdx.x >> 6);
  int lane = threadIdx.x & 63;
  const float* sp = skip + (size_t)row * 192;
  const float* qp = x_up + (size_t)row * 192;
  float sv[3], qv[3], ss = 0.f, qs = 0.f;
#pragma unroll
  for (int j = 0; j < 3; j++) {
    sv[j] = sp[lane + 64 * j]; qv[j] = qp[lane + 64 * j];
    ss += sv[j]; qs += qv[j];
  }
#pragma unroll
  for (int m = 1; m < 64; m <<= 1) { ss += __shfl_xor(ss, m, 64); qs += __shfl_xor(qs, m, 64); }
  float sm = ss * (1.f / 192.f), qm = qs * (1.f / 192.f);
  float s2 = 0.f, q2 = 0.f;
#pragma unroll
  for (int j = 0; j < 3; j++) { float d = sv[j] - sm; s2 += d * d; d = qv[j] - qm; q2 += d * d; }
#pragma unroll
  for (int m = 1; m < 64; m <<= 1) { s2 += __shfl_xor(s2, m, 64); q2 += __shfl_xor(q2, m, 64); }
  float sr = rsqrtf(s2 * (1.f / 192.f) + 1e-5f), qr = rsqrtf(q2 * (1.f / 192.f) + 1e-5f);
  int b = row >> 15, l = row & 32767;
  int s = l >> 10, h = (l >> 5) & 31, w = l & 31;
  int s_ = (s - SHIFT) & 31, h_ = (h - SHIFT) & 31, w_ = (w - SHIFT) & 31;
  int wIdx = ((s_ >> 2) * 8 + (h_ >> 2)) * 8 + (w_ >> 2);
  int n = ((s_ & 3) * 4 + (h_ & 3)) * 4 + (w_ & 3);
  size_t orow = ((size_t)(b * 512 + wIdx) * 64 + n) * 192;
  const float scale = 0.17677669529663687f;  // 32^-0.5
#pragma unroll
  for (int j = 0; j < 3; j++) {
    int cc = lane + 64 * j;
    float gg = gam[cc], bb = bet[cc];
    skw[orow + cc] = f2bf((sv[j] - sm) * sr * gg + bb);
    qw[orow + cc]  = f2bf(((qv[j] - qm) * qr * gg + bb) * scale);
  }
}

// ---------------- generic 64x64-tile GEMM: out = A[M][K] @ BT[N][K]^T + bias --------
// EPI 0: store bf16. EPI 1: gelu, store bf16. EPI 2: +res, store f32.
template <int EPI>
__global__ __launch_bounds__(256) void k_gemm64(
    const u16* __restrict__ A, const u16* __restrict__ BT,
    const float* __restrict__ bias, const float* __restrict__ res,
    float* __restrict__ outf, u16* __restrict__ outh, int Ncols, int K) {
  __shared__ u16 lA[64 * 200];
  __shared__ u16 lB[64 * 200];
  int mb = blockIdx.x, nb = blockIdx.y;
  int tid = threadIdx.x, lane = tid & 63, wv = tid >> 6, g = lane >> 4, c = lane & 15;
  f32x4 acc[4] = {};
  for (int k0 = 0; k0 < K; k0 += 192) {
    if (k0) __syncthreads();
    for (int ch = tid; ch < 1536; ch += 256) {
      int row = ch / 24, cc = ch % 24;
      *(u16x8*)&lA[row * 200 + cc * 8] =
          *(const u16x8*)&A[(size_t)(mb * 64 + row) * K + k0 + cc * 8];
      *(u16x8*)&lB[row * 200 + cc * 8] =
          *(const u16x8*)&BT[(size_t)(nb * 64 + row) * K + k0 + cc * 8];
    }
    __syncthreads();
#pragma unroll
    for (int ks = 0; ks < 6; ks++) {
      bf16x8 a = *(const bf16x8*)&lA[(wv * 16 + c) * 200 + ks * 32 + g * 8];
#pragma unroll
      for (int n = 0; n < 4; n++) {
        bf16x8 bfr = *(const bf16x8*)&lB[(n * 16 + c) * 200 + ks * 32 + g * 8];
        acc[n] = mfma16(a, bfr, acc[n]);
      }
    }
  }
#pragma unroll
  for (int n = 0; n < 4; n++)
#pragma unroll
    for (int r = 0; r < 4; r++) {
      int row = mb * 64 + wv * 16 + g * 4 + r;
      int col = nb * 64 + n * 16 + c;
      float v = acc[n][r] + bias[col];
      if (EPI == 0) {
        outh[(size_t)row * Ncols + col] = f2bf(v);
      } else if (EPI == 1) {
        v = 0.5f * v * (1.f + erff(v * 0.70710678118654752f));
        outh[(size_t)row * Ncols + col] = f2bf(v);
      } else {
        outf[(size_t)row * Ncols + col] = v + res[(size_t)row * Ncols + col];
      }
    }
}

// ---------------- K3: per-window attention (1 block/window, 1 wave/head) -------------
__global__ __launch_bounds__(384) void k_attn(
    const u16* __restrict__ qw, const u16* __restrict__ kvb,
    const float* __restrict__ rpb, const float* __restrict__ mask,
    u16* __restrict__ attn_o) {
  __shared__ u16 lq[64 * 200];
  __shared__ u16 lkv[64 * 392];
  __shared__ u16 lp[6][64 * 72];
  int b_ = blockIdx.x, wIdx = b_ & 511;
  int tid = threadIdx.x, lane = tid & 63, h = tid >> 6, g = lane >> 4, c = lane & 15;
  for (int ch = tid; ch < 1536; ch += 384) {
    int row = ch / 24, cc = ch % 24;
    *(u16x8*)&lq[row * 200 + cc * 8] =
        *(const u16x8*)&qw[((size_t)b_ * 64 + row) * 192 + cc * 8];
  }
  for (int ch = tid; ch < 3072; ch += 384) {
    int row = ch / 48, cc = ch % 48;
    *(u16x8*)&lkv[row * 392 + cc * 8] =
        *(const u16x8*)&kvb[((size_t)b_ * 64 + row) * 384 + cc * 8];
  }
  __syncthreads();
  // S = q @ k^T   (4x4 tiles of 16x16, K=32=hd in one mfma)
  bf16x8 kb[4];
#pragma unroll
  for (int n = 0; n < 4; n++)
    kb[n] = *(const bf16x8*)&lkv[(n * 16 + c) * 392 + h * 32 + g * 8];
  f32x4 acc[4][4] = {};
#pragma unroll
  for (int m = 0; m < 4; m++) {
    bf16x8 a = *(const bf16x8*)&lq[(m * 16 + c) * 200 + h * 32 + g * 8];
#pragma unroll
    for (int n = 0; n < 4; n++) acc[m][n] = mfma16(a, kb[n], acc[m][n]);
  }
  // + rpb + mask, row softmax, P -> LDS (bf16)
  const float* mrow = mask + (size_t)wIdx * 4096;
#pragma unroll
  for (int m = 0; m < 4; m++) {
#pragma unroll
    for (int r = 0; r < 4; r++) {
      int qr = m * 16 + g * 4 + r;
      int qs = qr >> 4, qh = (qr >> 2) & 3, qx = qr & 3;
      float vals[4];
#pragma unroll
      for (int n = 0; n < 4; n++) {
        int kc = n * 16 + c;
        int ks = kc >> 4, kh = (kc >> 2) & 3, kx = kc & 3;
        int idx = (qs - ks + 3) * 11 + (qh - kh + 3) * 7 + (qx - kx + 3);
        vals[n] = acc[m][n][r] + rpb[idx * 6 + h] + mrow[qr * 64 + kc];
      }
      float mx = fmaxf(fmaxf(vals[0], vals[1]), fmaxf(vals[2], vals[3]));
#pragma unroll
      for (int mm = 1; mm < 16; mm <<= 1) mx = fmaxf(mx, __shfl_xor(mx, mm, 64));
      float sum = 0.f;
#pragma unroll
      for (int n = 0; n < 4; n++) { vals[n] = expf(vals[n] - mx); sum += vals[n]; }
#pragma unroll
      for (int mm = 1; mm < 16; mm <<= 1) sum += __shfl_xor(sum, mm, 64);
      float inv = 1.f / sum;
#pragma unroll
      for (int n = 0; n < 4; n++) lp[h][qr * 72 + n * 16 + c] = f2bf(vals[n] * inv);
    }
  }
  // out = P @ v  (4m x 2n tiles, K=64 in 2 steps)
  bf16x8 vb[2][2];
#pragma unroll
  for (int k2 = 0; k2 < 2; k2++)
#pragma unroll
    for (int n = 0; n < 2; n++) {
      union { u16 u[8]; bf16x8 v; } bb;
#pragma unroll
      for (int j = 0; j < 8; j++)
        bb.u[j] = lkv[(k2 * 32 + g * 8 + j) * 392 + 192 + h * 32 + n * 16 + c];
      vb[k2][n] = bb.v;
    }
  f32x4 oacc[4][2] = {};
#pragma unroll
  for (int m = 0; m < 4; m++)
#pragma unroll
    for (int k2 = 0; k2 < 2; k2++) {
      bf16x8 a = *(const bf16x8*)&lp[h][(m * 16 + c) * 72 + k2 * 32 + g * 8];
#pragma unroll
      for (int n = 0; n < 2; n++) oacc[m][n] = mfma16(a, vb[k2][n], oacc[m][n]);
    }
#pragma unroll
  for (int m = 0; m < 4; m++)
#pragma unroll
    for (int n = 0; n < 2; n++)
#pragma unroll
      for (int r = 0; r < 4; r++) {
        int row = m * 16 + g * 4 + r, col = n * 16 + c;
        attn_o[((size_t)b_ * 64 + row) * 192 + h * 32 + col] = f2bf(oacc[m][n][r]);
      }
}

// ---------------- K4: proj GEMM + window-reverse scatter + residual + LN2 ------------
__global__ __launch_bounds__(256) void k_proj_ln(
    const u16* __restrict__ attn_o, const u16* __restrict__ prT,
    const float* __restrict__ proj_b, const float* __restrict__ x,
    const float* __restrict__ g2, const float* __restrict__ b2,
    float* __restrict__ y, u16* __restrict__ hn) {
  __shared__ u16 lA[64 * 200];
  __shared__ u16 lB[192 * 200];
  int b_ = blockIdx.x;
  int tid = threadIdx.x, lane = tid & 63, wv = tid >> 6, g = lane >> 4, c = lane & 15;
  for (int ch = tid; ch < 1536; ch += 256) {
    int row = ch / 24, cc = ch % 24;
    *(u16x8*)&lA[row * 200 + cc * 8] =
        *(const u16x8*)&attn_o[((size_t)b_ * 64 + row) * 192 + cc * 8];
  }
  for (int ch = tid; ch < 4608; ch += 256) {
    int row = ch / 24, cc = ch % 24;
    *(u16x8*)&lB[row * 200 + cc * 8] = *(const u16x8*)&prT[(size_t)row * 192 + cc * 8];
  }
  __syncthreads();
  f32x4 acc[12] = {};
#pragma unroll
  for (int ks = 0; ks < 6; ks++) {
    bf16x8 a = *(const bf16x8*)&lA[(wv * 16 + c) * 200 + ks * 32 + g * 8];
#pragma unroll
    for (int n = 0; n < 12; n++) {
      bf16x8 bfr = *(const bf16x8*)&lB[(n * 16 + c) * 200 + ks * 32 + g * 8];
      acc[n] = mfma16(a, bfr, acc[n]);
    }
  }
  int b = b_ >> 9, wIdx = b_ & 511;
  int wS = wIdx >> 6, wH = (wIdx >> 3) & 7, wW = wIdx & 7;
#pragma unroll
  for (int r = 0; r < 4; r++) {
    int tok = wv * 16 + g * 4 + r;
    int inS = tok >> 4, inH = (tok >> 2) & 3, inW = tok & 3;
    int s = (wS * 4 + inS + SHIFT) & 31;
    int hh = (wH * 4 + inH + SHIFT) & 31;
    int ww = (wW * 4 + inW + SHIFT) & 31;
    size_t l = ((size_t)s * 32 + hh) * 32 + ww;
    size_t base = ((size_t)b * 32768 + l) * 192;
    float vals[12], sum = 0.f;
#pragma unroll
    for (int n = 0; n < 12; n++) {
      int col = n * 16 + c;
      float v = acc[n][r] + proj_b[col] + x[base + col];
      vals[n] = v; sum += v;
    }
#pragma unroll
    for (int mm = 1; mm < 16; mm <<= 1) sum += __shfl_xor(sum, mm, 64);
    float mu = sum * (1.f / 192.f);
    float s2 = 0.f;
#pragma unroll
    for (int n = 0; n < 12; n++) { float d = vals[n] - mu; s2 += d * d; }
#pragma unroll
    for (int mm = 1; mm < 16; mm <<= 1) s2 += __shfl_xor(s2, mm, 64);
    float is = rsqrtf(s2 * (1.f / 192.f) + 1e-5f);
#pragma unroll
    for (int n = 0; n < 12; n++) {
      int col = n * 16 + c;
      y[base + col] = vals[n];
      hn[base + col] = f2bf((vals[n] - mu) * is * g2[col] + b2[col]);
    }
  }
}

extern "C" void kernel_launch(void* const* d_in, const int* in_sizes, int n_in,
                              void* d_out, int out_size, void* d_ws, size_t ws_size,
                              hipStream_t stream) {
  const float* x      = (const float*)d_in[0];
  const float* mask   = (const float*)d_in[1];
  const float* skip   = (const float*)d_in[2];
  const float* x_up   = (const float*)d_in[3];
  const float* n1g    = (const float*)d_in[4];
  const float* n1b    = (const float*)d_in[5];
  const float* kv_w   = (const float*)d_in[6];
  const float* kv_b   = (const float*)d_in[7];
  const float* rpb    = (const float*)d_in[8];
  const float* proj_w = (const float*)d_in[9];
  const float* proj_b = (const float*)d_in[10];
  const float* n2g    = (const float*)d_in[11];
  const float* n2b    = (const float*)d_in[12];
  const float* fc1_w  = (const float*)d_in[13];
  const float* fc1_b  = (const float*)d_in[14];
  const float* fc2_w  = (const float*)d_in[15];
  const float* fc2_b  = (const float*)d_in[16];
  char* ws = (char*)d_ws;
  u16* kvT  = (u16*)(ws + OFF_KVWT);
  u16* prT  = (u16*)(ws + OFF_PRWT);
  u16* f1T  = (u16*)(ws + OFF_FC1WT);
  u16* f2T  = (u16*)(ws + OFF_FC2WT);
  u16* skw  = (u16*)(ws + OFF_SKW);
  u16* qw   = (u16*)(ws + OFF_QW);
  u16* kvb  = (u16*)(ws + OFF_KVB);
  u16* h1   = (u16*)(ws + OFF_H1);
  u16* attn = (u16*)(ws + OFF_ATTN);
  float* y  = (float*)(ws + OFF_Y);
  u16* hn   = (u16*)(ws + OFF_HN);
  float* out = (float*)d_out;

  k_prep<<<dim3(576), dim3(256), 0, stream>>>(kv_w, proj_w, fc1_w, fc2_w, kvT, prT, f1T, f2T);
  k_ln_part<<<dim3(16384), dim3(256), 0, stream>>>(skip, x_up, n1g, n1b, skw, qw);
  k_gemm64<0><<<dim3(1024, 6), dim3(256), 0, stream>>>(skw, kvT, kv_b, nullptr, nullptr, kvb, 384, 192);
  k_attn<<<dim3(1024), dim3(384), 0, stream>>>(qw, kvb, rpb, mask, attn);
  k_proj_ln<<<dim3(1024), dim3(256), 0, stream>>>(attn, prT, proj_b, x, n2g, n2b, y, hn);
  k_gemm64<1><<<dim3(1024, 12), dim3(256), 0, stream>>>(hn, f1T, fc1_b, nullptr, nullptr, h1, 768, 192);
  k_gemm64<2><<<dim3(1024, 3), dim3(256), 0, stream>>>(h1, f2T, fc2_b, y, out, nullptr, 192, 768);
}

// Round 2
// 330.106 us; speedup vs baseline: 1.1025x; 1.1025x over previous
//
#include <hip/hip_runtime.h>
#include <math.h>

typedef unsigned short u16;
typedef __bf16 bf16x8 __attribute__((ext_vector_type(8)));
typedef float f32x4 __attribute__((ext_vector_type(4)));
typedef unsigned short u16x8 __attribute__((ext_vector_type(8)));

#define SHIFT 2

static __device__ __forceinline__ f32x4 mfma16(bf16x8 a, bf16x8 b, f32x4 c) {
  return __builtin_amdgcn_mfma_f32_16x16x32_bf16(a, b, c, 0, 0, 0);
}
static __device__ __forceinline__ u16 f2bf(float f) {
  unsigned u = __builtin_bit_cast(unsigned, f);
  unsigned r = u + 0x7fffu + ((u >> 16) & 1u);
  return (u16)(r >> 16);
}
static __device__ __forceinline__ float bf2f(u16 u) {
  unsigned v = (unsigned)u << 16;
  return __builtin_bit_cast(float, v);
}
// global -> LDS direct staging; lbase must be wave-uniform (HW adds lane*16B)
static __device__ __forceinline__ void stage16(const u16* g, u16* lbase, int lane) {
#if __has_builtin(__builtin_amdgcn_global_load_lds)
  __builtin_amdgcn_global_load_lds(
      (const __attribute__((address_space(1))) unsigned int*)g,
      (__attribute__((address_space(3))) unsigned int*)lbase, 16, 0, 0);
#else
  *(u16x8*)(lbase + lane * 8) = *(const u16x8*)g;
#endif
}

// ---------------- workspace layout (bytes) ----------------
#define OFF_KVWT  ((size_t)0)                          // 384x192 bf16
#define OFF_PRWT  (OFF_KVWT + 384*192*2)               // 192x192
#define OFF_FC1WT (OFF_PRWT + 192*192*2)               // 768x192
#define OFF_FC2WT (OFF_FC1WT + 768*192*2)              // 192x768
#define OFF_SKW   (OFF_FC2WT + 192*768*2)              // 65536x192 bf16 (window order)
#define OFF_QW    (OFF_SKW + (size_t)65536*192*2)
#define OFF_KVB   (OFF_QW + (size_t)65536*192*2)       // 65536x384 bf16
#define OFF_H1    OFF_SKW                              // 65536x768 bf16, aliases skw+qw+kvb
#define OFF_ATTN  (OFF_KVB + (size_t)65536*384*2)      // 65536x192 bf16 (window order)
#define OFF_HN    (OFF_ATTN + (size_t)65536*192*2)     // 65536x192 bf16 (natural)
#define OFF_PO    (OFF_HN + (size_t)65536*192*2)       // 65536x192 bf16 (natural)
// total = OFF_PO + 65536*192*2 = 176,971,776 B

// ---------------- K0: weight transpose + f32->bf16 ----------------
__global__ __launch_bounds__(256) void k_prep(
    const float* __restrict__ kv_w, const float* __restrict__ proj_w,
    const float* __restrict__ fc1_w, const float* __restrict__ fc2_w,
    u16* __restrict__ kvT, u16* __restrict__ prT,
    u16* __restrict__ f1T, u16* __restrict__ f2T) {
  int i = blockIdx.x * 256 + threadIdx.x;
  if (i < 192 * 384) kvT[(i % 384) * 192 + i / 384] = f2bf(kv_w[i]);
  if (i < 192 * 192) prT[(i % 192) * 192 + i / 192] = f2bf(proj_w[i]);
  if (i < 192 * 768) f1T[(i % 768) * 192 + i / 768] = f2bf(fc1_w[i]);
  if (i < 768 * 192) f2T[(i % 192) * 768 + i / 192] = f2bf(fc2_w[i]);
}

// ---------------- K1: LN + cyclic shift + window partition ----------------
__global__ __launch_bounds__(256) void k_ln_part(
    const float* __restrict__ skip, const float* __restrict__ x_up,
    const float* __restrict__ gam, const float* __restrict__ bet,
    u16* __restrict__ skw, u16* __restrict__ qw) {
  int row = blockIdx.x * 4 + (threadIdx.x >> 6);
  int lane = threadIdx.x & 63;
  const float* sp = skip + (size_t)row * 192;
  const float* qp = x_up + (size_t)row * 192;
  float sv[3], qv[3], ss = 0.f, qs = 0.f;
#pragma unroll
  for (int j = 0; j < 3; j++) {
    sv[j] = sp[lane + 64 * j]; qv[j] = qp[lane + 64 * j];
    ss += sv[j]; qs += qv[j];
  }
#pragma unroll
  for (int m = 1; m < 64; m <<= 1) { ss += __shfl_xor(ss, m, 64); qs += __shfl_xor(qs, m, 64); }
  float sm = ss * (1.f / 192.f), qm = qs * (1.f / 192.f);
  float s2 = 0.f, q2 = 0.f;
#pragma unroll
  for (int j = 0; j < 3; j++) { float d = sv[j] - sm; s2 += d * d; d = qv[j] - qm; q2 += d * d; }
#pragma unroll
  for (int m = 1; m < 64; m <<= 1) { s2 += __shfl_xor(s2, m, 64); q2 += __shfl_xor(q2, m, 64); }
  float sr = rsqrtf(s2 * (1.f / 192.f) + 1e-5f), qr = rsqrtf(q2 * (1.f / 192.f) + 1e-5f);
  int b = row >> 15, l = row & 32767;
  int s = l >> 10, h = (l >> 5) & 31, w = l & 31;
  int s_ = (s - SHIFT) & 31, h_ = (h - SHIFT) & 31, w_ = (w - SHIFT) & 31;
  int wIdx = ((s_ >> 2) * 8 + (h_ >> 2)) * 8 + (w_ >> 2);
  int n = ((s_ & 3) * 4 + (h_ & 3)) * 4 + (w_ & 3);
  size_t orow = ((size_t)(b * 512 + wIdx) * 64 + n) * 192;
  const float scale = 0.17677669529663687f;  // 32^-0.5
#pragma unroll
  for (int j = 0; j < 3; j++) {
    int cc = lane + 64 * j;
    float gg = gam[cc], bb = bet[cc];
    skw[orow + cc] = f2bf((sv[j] - sm) * sr * gg + bb);
    qw[orow + cc]  = f2bf(((qv[j] - qm) * qr * gg + bb) * scale);
  }
}

// ---------------- 128-row-tile GEMM (m97 structure): out = A @ BT^T + bias --------
// 256 thr = 4 waves (2x2), per-wave 64 x BN/2 output, global_load_lds staging, BK=64.
// EPI 0: store bf16. EPI 1: gelu -> bf16. EPI 2: + x + po -> f32 out.
template <int BN, int EPI>
__global__ __launch_bounds__(256) void k_gemm128(
    const u16* __restrict__ A, const u16* __restrict__ BT,
    const float* __restrict__ bias, const float* __restrict__ xres,
    const u16* __restrict__ po, float* __restrict__ outf,
    u16* __restrict__ outh, int Ncols, int K) {
  constexpr int NF = BN / 32;   // b-fragments per wave (4 or 6)
  constexpr int HN = BN / 2;    // wave col-span
  __shared__ u16 lds[(128 + BN) * 64];
  int mb = blockIdx.x, nb = blockIdx.y;
  int tid = threadIdx.x, w = tid >> 6, l = tid & 63;
  int wr = w >> 1, wc = w & 1, g = l >> 4, c = l & 15;
  f32x4 acc[4][NF] = {};
  const int KS = K / 64;
  for (int ks = 0; ks < KS; ks++) {
    if (ks) __syncthreads();
    int k0 = ks * 64;
#pragma unroll
    for (int i = 0; i < 4; i++) {
      int s = w * 4 + i;
      stage16(&A[(size_t)(mb * 128 + s * 8 + (l >> 3)) * K + k0 + (l & 7) * 8],
              &lds[s * 512], l);
    }
#pragma unroll
    for (int i = 0; i < NF; i++) {
      int s = w * NF + i;
      stage16(&BT[(size_t)(nb * BN + s * 8 + (l >> 3)) * K + k0 + (l & 7) * 8],
              &lds[8192 + s * 512], l);
    }
    __syncthreads();
#pragma unroll
    for (int kk = 0; kk < 2; kk++) {
      bf16x8 a[4];
#pragma unroll
      for (int m = 0; m < 4; m++)
        a[m] = *(const bf16x8*)&lds[(wr * 64 + m * 16 + c) * 64 + kk * 32 + g * 8];
#pragma unroll
      for (int n = 0; n < NF; n++) {
        bf16x8 b = *(const bf16x8*)&lds[8192 + (wc * HN + n * 16 + c) * 64 + kk * 32 + g * 8];
#pragma unroll
        for (int m = 0; m < 4; m++) acc[m][n] = mfma16(a[m], b, acc[m][n]);
      }
    }
  }
#pragma unroll
  for (int m = 0; m < 4; m++)
#pragma unroll
    for (int n = 0; n < NF; n++)
#pragma unroll
      for (int r = 0; r < 4; r++) {
        int row = mb * 128 + wr * 64 + m * 16 + g * 4 + r;
        int col = nb * BN + wc * HN + n * 16 + c;
        float v = acc[m][n][r] + bias[col];
        size_t base = (size_t)row * Ncols + col;
        if (EPI == 0) {
          outh[base] = f2bf(v);
        } else if (EPI == 1) {
          v = 0.5f * v * (1.f + erff(v * 0.70710678118654752f));
          outh[base] = f2bf(v);
        } else {
          outf[base] = v + xres[base] + bf2f(po[base]);
        }
      }
}

// ---------------- K3: per-window attention (1 block/window, 1 wave/head) -------------
__global__ __launch_bounds__(384) void k_attn(
    const u16* __restrict__ qw, const u16* __restrict__ kvb,
    const float* __restrict__ rpb, const float* __restrict__ mask,
    u16* __restrict__ attn_o) {
  __shared__ u16 lq[64 * 200];
  __shared__ u16 lkv[64 * 392];
  __shared__ u16 lp[6][64 * 72];
  int b_ = blockIdx.x, wIdx = b_ & 511;
  int tid = threadIdx.x, lane = tid & 63, h = tid >> 6, g = lane >> 4, c = lane & 15;
  for (int ch = tid; ch < 1536; ch += 384) {
    int row = ch / 24, cc = ch % 24;
    *(u16x8*)&lq[row * 200 + cc * 8] =
        *(const u16x8*)&qw[((size_t)b_ * 64 + row) * 192 + cc * 8];
  }
  for (int ch = tid; ch < 3072; ch += 384) {
    int row = ch / 48, cc = ch % 48;
    *(u16x8*)&lkv[row * 392 + cc * 8] =
        *(const u16x8*)&kvb[((size_t)b_ * 64 + row) * 384 + cc * 8];
  }
  __syncthreads();
  bf16x8 kb[4];
#pragma unroll
  for (int n = 0; n < 4; n++)
    kb[n] = *(const bf16x8*)&lkv[(n * 16 + c) * 392 + h * 32 + g * 8];
  f32x4 acc[4][4] = {};
#pragma unroll
  for (int m = 0; m < 4; m++) {
    bf16x8 a = *(const bf16x8*)&lq[(m * 16 + c) * 200 + h * 32 + g * 8];
#pragma unroll
    for (int n = 0; n < 4; n++) acc[m][n] = mfma16(a, kb[n], acc[m][n]);
  }
  const float* mrow = mask + (size_t)wIdx * 4096;
#pragma unroll
  for (int m = 0; m < 4; m++) {
#pragma unroll
    for (int r = 0; r < 4; r++) {
      int qr = m * 16 + g * 4 + r;
      int qs = qr >> 4, qh = (qr >> 2) & 3, qx = qr & 3;
      float vals[4];
#pragma unroll
      for (int n = 0; n < 4; n++) {
        int kc = n * 16 + c;
        int ks = kc >> 4, kh = (kc >> 2) & 3, kx = kc & 3;
        int idx = (qs - ks + 3) * 11 + (qh - kh + 3) * 7 + (qx - kx + 3);
        vals[n] = acc[m][n][r] + rpb[idx * 6 + h] + mrow[qr * 64 + kc];
      }
      float mx = fmaxf(fmaxf(vals[0], vals[1]), fmaxf(vals[2], vals[3]));
#pragma unroll
      for (int mm = 1; mm < 16; mm <<= 1) mx = fmaxf(mx, __shfl_xor(mx, mm, 64));
      float sum = 0.f;
#pragma unroll
      for (int n = 0; n < 4; n++) { vals[n] = expf(vals[n] - mx); sum += vals[n]; }
#pragma unroll
      for (int mm = 1; mm < 16; mm <<= 1) sum += __shfl_xor(sum, mm, 64);
      float inv = 1.f / sum;
#pragma unroll
      for (int n = 0; n < 4; n++) lp[h][qr * 72 + n * 16 + c] = f2bf(vals[n] * inv);
    }
  }
  bf16x8 vb[2][2];
#pragma unroll
  for (int k2 = 0; k2 < 2; k2++)
#pragma unroll
    for (int n = 0; n < 2; n++) {
      union { u16 u[8]; bf16x8 v; } bb;
#pragma unroll
      for (int j = 0; j < 8; j++)
        bb.u[j] = lkv[(k2 * 32 + g * 8 + j) * 392 + 192 + h * 32 + n * 16 + c];
      vb[k2][n] = bb.v;
    }
  f32x4 oacc[4][2] = {};
#pragma unroll
  for (int m = 0; m < 4; m++)
#pragma unroll
    for (int k2 = 0; k2 < 2; k2++) {
      bf16x8 a = *(const bf16x8*)&lp[h][(m * 16 + c) * 72 + k2 * 32 + g * 8];
#pragma unroll
      for (int n = 0; n < 2; n++) oacc[m][n] = mfma16(a, vb[k2][n], oacc[m][n]);
    }
#pragma unroll
  for (int m = 0; m < 4; m++)
#pragma unroll
    for (int n = 0; n < 2; n++)
#pragma unroll
      for (int r = 0; r < 4; r++) {
        int row = m * 16 + g * 4 + r, col = n * 16 + c;
        attn_o[((size_t)b_ * 64 + row) * 192 + h * 32 + col] = f2bf(oacc[m][n][r]);
      }
}

// ---------------- K4: proj GEMM (128x192) + scatter + residual + LN2 epilogue -------
// writes po = proj_out + proj_b (bf16, natural) and hn = LN(x + po) (bf16, natural)
__global__ __launch_bounds__(256) void k_proj128(
    const u16* __restrict__ attn_o, const u16* __restrict__ prT,
    const float* __restrict__ proj_b, const float* __restrict__ x,
    const float* __restrict__ g2, const float* __restrict__ b2,
    u16* __restrict__ hn, u16* __restrict__ po) {
  __shared__ u16 lds[(128 + 192) * 64];
  int mb = blockIdx.x;
  int tid = threadIdx.x, w = tid >> 6, l = tid & 63;
  int wr = w >> 1, wc = w & 1, g = l >> 4, c = l & 15;
  f32x4 acc[4][6] = {};
  for (int ks = 0; ks < 3; ks++) {
    if (ks) __syncthreads();
    int k0 = ks * 64;
#pragma unroll
    for (int i = 0; i < 4; i++) {
      int s = w * 4 + i;
      stage16(&attn_o[(size_t)(mb * 128 + s * 8 + (l >> 3)) * 192 + k0 + (l & 7) * 8],
              &lds[s * 512], l);
    }
#pragma unroll
    for (int i = 0; i < 6; i++) {
      int s = w * 6 + i;
      stage16(&prT[(size_t)(s * 8 + (l >> 3)) * 192 + k0 + (l & 7) * 8],
              &lds[8192 + s * 512], l);
    }
    __syncthreads();
#pragma unroll
    for (int kk = 0; kk < 2; kk++) {
      bf16x8 a[4];
#pragma unroll
      for (int m = 0; m < 4; m++)
        a[m] = *(const bf16x8*)&lds[(wr * 64 + m * 16 + c) * 64 + kk * 32 + g * 8];
#pragma unroll
      for (int n = 0; n < 6; n++) {
        bf16x8 b = *(const bf16x8*)&lds[8192 + (wc * 96 + n * 16 + c) * 64 + kk * 32 + g * 8];
#pragma unroll
        for (int m = 0; m < 4; m++) acc[m][n] = mfma16(a[m], b, acc[m][n]);
      }
    }
  }
  __syncthreads();  // lds reused for LN partials
  float* pf = (float*)lds;
  unsigned bases[4][4];
#pragma unroll
  for (int m = 0; m < 4; m++)
#pragma unroll
    for (int r = 0; r < 4; r++) {
      int rowl = wr * 64 + m * 16 + g * 4 + r;
      int b_ = mb * 2 + (rowl >> 6);
      int tok = rowl & 63;
      int bI = b_ >> 9, wIdx = b_ & 511;
      int wS = wIdx >> 6, wH = (wIdx >> 3) & 7, wW = wIdx & 7;
      int inS = tok >> 4, inH = (tok >> 2) & 3, inW = tok & 3;
      int s = (wS * 4 + inS + SHIFT) & 31;
      int hh = (wH * 4 + inH + SHIFT) & 31;
      int ww = (wW * 4 + inW + SHIFT) & 31;
      unsigned base = ((unsigned)(bI * 32768) + ((unsigned)s * 32 + hh) * 32 + ww) * 192u;
      bases[m][r] = base;
      float sum = 0.f, sq = 0.f;
#pragma unroll
      for (int n = 0; n < 6; n++) {
        int col = wc * 96 + n * 16 + c;
        float v = acc[m][n][r] + proj_b[col];
        po[base + col] = f2bf(v);
        float y = v + x[base + col];
        acc[m][n][r] = y;
        sum += y; sq += y * y;
      }
#pragma unroll
      for (int mm = 1; mm < 16; mm <<= 1) { sum += __shfl_xor(sum, mm, 64); sq += __shfl_xor(sq, mm, 64); }
      if (c == 0) { pf[rowl * 4 + wc * 2] = sum; pf[rowl * 4 + wc * 2 + 1] = sq; }
    }
  __syncthreads();
#pragma unroll
  for (int m = 0; m < 4; m++)
#pragma unroll
    for (int r = 0; r < 4; r++) {
      int rowl = wr * 64 + m * 16 + g * 4 + r;
      float mu = (pf[rowl * 4] + pf[rowl * 4 + 2]) * (1.f / 192.f);
      float q  = (pf[rowl * 4 + 1] + pf[rowl * 4 + 3]) * (1.f / 192.f);
      float rs = rsqrtf(q - mu * mu + 1e-5f);
      unsigned base = bases[m][r];
#pragma unroll
      for (int n = 0; n < 6; n++) {
        int col = wc * 96 + n * 16 + c;
        hn[base + col] = f2bf((acc[m][n][r] - mu) * rs * g2[col] + b2[col]);
      }
    }
}

extern "C" void kernel_launch(void* const* d_in, const int* in_sizes, int n_in,
                              void* d_out, int out_size, void* d_ws, size_t ws_size,
                              hipStream_t stream) {
  const float* x      = (const float*)d_in[0];
  const float* mask   = (const float*)d_in[1];
  const float* skip   = (const float*)d_in[2];
  const float* x_up   = (const float*)d_in[3];
  const float* n1g    = (const float*)d_in[4];
  const float* n1b    = (const float*)d_in[5];
  const float* kv_w   = (const float*)d_in[6];
  const float* kv_b   = (const float*)d_in[7];
  const float* rpb    = (const float*)d_in[8];
  const float* proj_w = (const float*)d_in[9];
  const float* proj_b = (const float*)d_in[10];
  const float* n2g    = (const float*)d_in[11];
  const float* n2b    = (const float*)d_in[12];
  const float* fc1_w  = (const float*)d_in[13];
  const float* fc1_b  = (const float*)d_in[14];
  const float* fc2_w  = (const float*)d_in[15];
  const float* fc2_b  = (const float*)d_in[16];
  char* ws = (char*)d_ws;
  u16* kvT  = (u16*)(ws + OFF_KVWT);
  u16* prT  = (u16*)(ws + OFF_PRWT);
  u16* f1T  = (u16*)(ws + OFF_FC1WT);
  u16* f2T  = (u16*)(ws + OFF_FC2WT);
  u16* skw  = (u16*)(ws + OFF_SKW);
  u16* qw   = (u16*)(ws + OFF_QW);
  u16* kvb  = (u16*)(ws + OFF_KVB);
  u16* h1   = (u16*)(ws + OFF_H1);
  u16* attn = (u16*)(ws + OFF_ATTN);
  u16* hn   = (u16*)(ws + OFF_HN);
  u16* po   = (u16*)(ws + OFF_PO);
  float* out = (float*)d_out;

  k_prep<<<dim3(576), dim3(256), 0, stream>>>(kv_w, proj_w, fc1_w, fc2_w, kvT, prT, f1T, f2T);
  k_ln_part<<<dim3(16384), dim3(256), 0, stream>>>(skip, x_up, n1g, n1b, skw, qw);
  k_gemm128<128, 0><<<dim3(512, 3), dim3(256), 0, stream>>>(
      skw, kvT, kv_b, nullptr, nullptr, nullptr, kvb, 384, 192);
  k_attn<<<dim3(1024), dim3(384), 0, stream>>>(qw, kvb, rpb, mask, attn);
  k_proj128<<<dim3(512), dim3(256), 0, stream>>>(attn, prT, proj_b, x, n2g, n2b, hn, po);
  k_gemm128<128, 1><<<dim3(512, 6), dim3(256), 0, stream>>>(
      hn, f1T, fc1_b, nullptr, nullptr, nullptr, h1, 768, 192);
  k_gemm128<192, 2><<<dim3(512, 1), dim3(256), 0, stream>>>(
      h1, f2T, fc2_b, x, po, out, nullptr, 192, 768);
}

// Round 3
// 310.418 us; speedup vs baseline: 1.1724x; 1.0634x over previous
//
#include <hip/hip_runtime.h>
#include <math.h>

typedef unsigned short u16;
typedef __bf16 bf16x8 __attribute__((ext_vector_type(8)));
typedef float f32x4 __attribute__((ext_vector_type(4)));
typedef unsigned short u16x8 __attribute__((ext_vector_type(8)));

#define SHIFT 2

static __device__ __forceinline__ f32x4 mfma16(bf16x8 a, bf16x8 b, f32x4 c) {
  return __builtin_amdgcn_mfma_f32_16x16x32_bf16(a, b, c, 0, 0, 0);
}
static __device__ __forceinline__ u16 f2bf(float f) {
  unsigned u = __builtin_bit_cast(unsigned, f);
  unsigned r = u + 0x7fffu + ((u >> 16) & 1u);
  return (u16)(r >> 16);
}
static __device__ __forceinline__ float bf2f(u16 u) {
  unsigned v = (unsigned)u << 16;
  return __builtin_bit_cast(float, v);
}
static __device__ __forceinline__ void stage16(const u16* g, u16* lbase, int lane) {
#if __has_builtin(__builtin_amdgcn_global_load_lds)
  __builtin_amdgcn_global_load_lds(
      (const __attribute__((address_space(1))) unsigned int*)g,
      (__attribute__((address_space(3))) unsigned int*)lbase, 16, 0, 0);
#else
  *(u16x8*)(lbase + lane * 8) = *(const u16x8*)g;
#endif
}

// ---------------- workspace layout (bytes) ----------------
#define OFF_KVWT  ((size_t)0)                          // 384x192 bf16
#define OFF_PRWT  (OFF_KVWT + 384*192*2)               // 192x192
#define OFF_FC1WT (OFF_PRWT + 192*192*2)               // 768x192
#define OFF_FC2WT (OFF_FC1WT + 768*192*2)              // 192x768
#define OFF_SKW   (OFF_FC2WT + 192*768*2)              // 65536x192 bf16 (window order)
#define OFF_QW    (OFF_SKW + (size_t)65536*192*2)
#define OFF_KVB   (OFF_QW + (size_t)65536*192*2)       // 65536x384 bf16 (window order)
#define OFF_HN    (OFF_KVB + (size_t)65536*384*2)      // 65536x192 bf16 (natural)
#define OFF_PO    (OFF_HN + (size_t)65536*192*2)       // 65536x192 bf16 (natural)
// total = OFF_PO + 65536*192*2 = 151,805,952 B

// ---------------- K0: weight transpose + f32->bf16 ----------------
__global__ __launch_bounds__(256) void k_prep(
    const float* __restrict__ kv_w, const float* __restrict__ proj_w,
    const float* __restrict__ fc1_w, const float* __restrict__ fc2_w,
    u16* __restrict__ kvT, u16* __restrict__ prT,
    u16* __restrict__ f1T, u16* __restrict__ f2T) {
  int i = blockIdx.x * 256 + threadIdx.x;
  if (i < 192 * 384) kvT[(i % 384) * 192 + i / 384] = f2bf(kv_w[i]);
  if (i < 192 * 192) prT[(i % 192) * 192 + i / 192] = f2bf(proj_w[i]);
  if (i < 192 * 768) f1T[(i % 768) * 192 + i / 768] = f2bf(fc1_w[i]);
  if (i < 768 * 192) f2T[(i % 192) * 768 + i / 192] = f2bf(fc2_w[i]);
}

// ---------------- K1: LN + cyclic shift + window partition ----------------
__global__ __launch_bounds__(256) void k_ln_part(
    const float* __restrict__ skip, const float* __restrict__ x_up,
    const float* __restrict__ gam, const float* __restrict__ bet,
    u16* __restrict__ skw, u16* __restrict__ qw) {
  int row = blockIdx.x * 4 + (threadIdx.x >> 6);
  int lane = threadIdx.x & 63;
  const float* sp = skip + (size_t)row * 192;
  const float* qp = x_up + (size_t)row * 192;
  float sv[3], qv[3], ss = 0.f, qs = 0.f;
#pragma unroll
  for (int j = 0; j < 3; j++) {
    sv[j] = sp[lane + 64 * j]; qv[j] = qp[lane + 64 * j];
    ss += sv[j]; qs += qv[j];
  }
#pragma unroll
  for (int m = 1; m < 64; m <<= 1) { ss += __shfl_xor(ss, m, 64); qs += __shfl_xor(qs, m, 64); }
  float sm = ss * (1.f / 192.f), qm = qs * (1.f / 192.f);
  float s2 = 0.f, q2 = 0.f;
#pragma unroll
  for (int j = 0; j < 3; j++) { float d = sv[j] - sm; s2 += d * d; d = qv[j] - qm; q2 += d * d; }
#pragma unroll
  for (int m = 1; m < 64; m <<= 1) { s2 += __shfl_xor(s2, m, 64); q2 += __shfl_xor(q2, m, 64); }
  float sr = rsqrtf(s2 * (1.f / 192.f) + 1e-5f), qr = rsqrtf(q2 * (1.f / 192.f) + 1e-5f);
  int b = row >> 15, l = row & 32767;
  int s = l >> 10, h = (l >> 5) & 31, w = l & 31;
  int s_ = (s - SHIFT) & 31, h_ = (h - SHIFT) & 31, w_ = (w - SHIFT) & 31;
  int wIdx = ((s_ >> 2) * 8 + (h_ >> 2)) * 8 + (w_ >> 2);
  int n = ((s_ & 3) * 4 + (h_ & 3)) * 4 + (w_ & 3);
  size_t orow = ((size_t)(b * 512 + wIdx) * 64 + n) * 192;
  const float scale = 0.17677669529663687f;  // 32^-0.5
#pragma unroll
  for (int j = 0; j < 3; j++) {
    int cc = lane + 64 * j;
    float gg = gam[cc], bb = bet[cc];
    skw[orow + cc] = f2bf((sv[j] - sm) * sr * gg + bb);
    qw[orow + cc]  = f2bf(((qv[j] - qm) * qr * gg + bb) * scale);
  }
}

// ---------------- K2: kv GEMM (unchanged m97-style control) ----------------
__global__ __launch_bounds__(256) void k_kv(
    const u16* __restrict__ A, const u16* __restrict__ BT,
    const float* __restrict__ bias, u16* __restrict__ outh) {
  __shared__ u16 lds[(128 + 128) * 64];
  int mb = blockIdx.x, nb = blockIdx.y;
  int tid = threadIdx.x, w = tid >> 6, l = tid & 63;
  int wr = w >> 1, wc = w & 1, g = l >> 4, c = l & 15;
  f32x4 acc[4][4] = {};
  for (int ks = 0; ks < 3; ks++) {
    if (ks) __syncthreads();
    int k0 = ks * 64;
#pragma unroll
    for (int i = 0; i < 4; i++) {
      int s = w * 4 + i;
      stage16(&A[(size_t)(mb * 128 + s * 8 + (l >> 3)) * 192 + k0 + (l & 7) * 8],
              &lds[s * 512], l);
      stage16(&BT[(size_t)(nb * 128 + s * 8 + (l >> 3)) * 192 + k0 + (l & 7) * 8],
              &lds[8192 + s * 512], l);
    }
    __syncthreads();
#pragma unroll
    for (int kk = 0; kk < 2; kk++) {
      bf16x8 a[4];
#pragma unroll
      for (int m = 0; m < 4; m++)
        a[m] = *(const bf16x8*)&lds[(wr * 64 + m * 16 + c) * 64 + kk * 32 + g * 8];
#pragma unroll
      for (int n = 0; n < 4; n++) {
        bf16x8 b = *(const bf16x8*)&lds[8192 + (wc * 64 + n * 16 + c) * 64 + kk * 32 + g * 8];
#pragma unroll
        for (int m = 0; m < 4; m++) acc[m][n] = mfma16(a[m], b, acc[m][n]);
      }
    }
  }
#pragma unroll
  for (int m = 0; m < 4; m++)
#pragma unroll
    for (int n = 0; n < 4; n++)
#pragma unroll
      for (int r = 0; r < 4; r++) {
        int row = mb * 128 + wr * 64 + m * 16 + g * 4 + r;
        int col = nb * 128 + wc * 64 + n * 16 + c;
        outh[(size_t)row * 384 + col] = f2bf(acc[m][n][r] + bias[col]);
      }
}

// ---------------- K3: fused attention + proj + residual + LN2 -----------------
// 1 block = 1 window (64 tokens); 384 thr = 6 waves = 1 head each for attn,
// then 32-col strips each for proj. Q/K fragments direct from global.
__global__ __launch_bounds__(384) void k_attn_mega(
    const u16* __restrict__ qw, const u16* __restrict__ kvb,
    const float* __restrict__ rpb, const float* __restrict__ mask,
    const u16* __restrict__ prT, const float* __restrict__ proj_b,
    const float* __restrict__ x, const float* __restrict__ g2,
    const float* __restrict__ b2, u16* __restrict__ hn, u16* __restrict__ po) {
  __shared__ u16 lv[64 * 200];       // V tile (row-major, padded)
  __shared__ u16 lp[6][16 * 72];     // per-head P m-slice
  __shared__ u16 lo[64 * 200];       // attention output tile
  __shared__ float pf[64 * 16];      // LN partials
  int b_ = blockIdx.x, wIdx = b_ & 511;
  int tid = threadIdx.x, l = tid & 63, wv = tid >> 6, g = l >> 4, c = l & 15;
  // stage V (cols 192..383 of kvb)
#pragma unroll
  for (int i = 0; i < 4; i++) {
    int cid = tid + i * 384;
    int row = cid / 24, ch = cid % 24;
    *(u16x8*)&lv[row * 200 + ch * 8] =
        *(const u16x8*)&kvb[((size_t)b_ * 64 + row) * 384 + 192 + ch * 8];
  }
  __syncthreads();
  int h = wv;
  // ---- QK^T: fragments direct from global ----
  bf16x8 qa[4], kb[4];
#pragma unroll
  for (int m = 0; m < 4; m++)
    qa[m] = *(const bf16x8*)&qw[((size_t)b_ * 64 + m * 16 + c) * 192 + h * 32 + g * 8];
#pragma unroll
  for (int n = 0; n < 4; n++)
    kb[n] = *(const bf16x8*)&kvb[((size_t)b_ * 64 + n * 16 + c) * 384 + h * 32 + g * 8];
  f32x4 acc[4][4] = {};
#pragma unroll
  for (int m = 0; m < 4; m++)
#pragma unroll
    for (int n = 0; n < 4; n++) acc[m][n] = mfma16(qa[m], kb[n], acc[m][n]);
  // ---- V fragments (packed scalar reads, reused across m) ----
  bf16x8 vb[2][2];
#pragma unroll
  for (int kk = 0; kk < 2; kk++)
#pragma unroll
    for (int nd = 0; nd < 2; nd++) {
      union { u16 u[8]; bf16x8 v; } bb;
#pragma unroll
      for (int j = 0; j < 8; j++)
        bb.u[j] = lv[(kk * 32 + g * 8 + j) * 200 + h * 32 + nd * 16 + c];
      vb[kk][nd] = bb.v;
    }
  // ---- softmax per m-slice, then PV partial ----
  const float* mrow = mask + (size_t)wIdx * 4096;
  f32x4 oacc[4][2] = {};
#pragma unroll
  for (int m = 0; m < 4; m++) {
#pragma unroll
    for (int r = 0; r < 4; r++) {
      int qr = m * 16 + g * 4 + r;
      int qs = qr >> 4, qh = (qr >> 2) & 3, qx = qr & 3;
      float vals[4];
#pragma unroll
      for (int n = 0; n < 4; n++) {
        int kc = n * 16 + c;
        int ks = kc >> 4, kh = (kc >> 2) & 3, kx = kc & 3;
        int idx = (qs - ks + 3) * 11 + (qh - kh + 3) * 7 + (qx - kx + 3);
        vals[n] = acc[m][n][r] + rpb[idx * 6 + h] + mrow[qr * 64 + kc];
      }
      float mx = fmaxf(fmaxf(vals[0], vals[1]), fmaxf(vals[2], vals[3]));
#pragma unroll
      for (int mm = 1; mm < 16; mm <<= 1) mx = fmaxf(mx, __shfl_xor(mx, mm, 64));
      float sum = 0.f;
#pragma unroll
      for (int n = 0; n < 4; n++) { vals[n] = __expf(vals[n] - mx); sum += vals[n]; }
#pragma unroll
      for (int mm = 1; mm < 16; mm <<= 1) sum += __shfl_xor(sum, mm, 64);
      float inv = 1.f / sum;
#pragma unroll
      for (int n = 0; n < 4; n++)
        lp[h][(g * 4 + r) * 72 + n * 16 + c] = f2bf(vals[n] * inv);
    }
    // PV for this m-slice (same wave wrote lp[h]; lgkmcnt handled by compiler)
#pragma unroll
    for (int kk = 0; kk < 2; kk++) {
      bf16x8 pa = *(const bf16x8*)&lp[h][c * 72 + kk * 32 + g * 8];
#pragma unroll
      for (int nd = 0; nd < 2; nd++) oacc[m][nd] = mfma16(pa, vb[kk][nd], oacc[m][nd]);
    }
  }
  // ---- attention output -> LDS ----
#pragma unroll
  for (int m = 0; m < 4; m++)
#pragma unroll
    for (int nd = 0; nd < 2; nd++)
#pragma unroll
      for (int r = 0; r < 4; r++)
        lo[(m * 16 + g * 4 + r) * 200 + h * 32 + nd * 16 + c] = f2bf(oacc[m][nd][r]);
  __syncthreads();
  // ---- proj: wave wv owns cols wv*32..+31, K=192 ----
  f32x4 pacc[4][2] = {};
#pragma unroll
  for (int ks = 0; ks < 6; ks++) {
    bf16x8 pa[4];
#pragma unroll
    for (int m = 0; m < 4; m++)
      pa[m] = *(const bf16x8*)&lo[(m * 16 + c) * 200 + ks * 32 + g * 8];
#pragma unroll
    for (int n = 0; n < 2; n++) {
      bf16x8 pb = *(const bf16x8*)&prT[(size_t)(wv * 32 + n * 16 + c) * 192 + ks * 32 + g * 8];
#pragma unroll
      for (int m = 0; m < 4; m++) pacc[m][n] = mfma16(pa[m], pb, pacc[m][n]);
    }
  }
  // ---- epilogue: scatter + residual + LN2 ----
  int bI = b_ >> 9;
  int wS = wIdx >> 6, wH = (wIdx >> 3) & 7, wW = wIdx & 7;
  float yv[4][2][4];
#pragma unroll
  for (int m = 0; m < 4; m++)
#pragma unroll
    for (int r = 0; r < 4; r++) {
      int tok = m * 16 + g * 4 + r;
      int inS = tok >> 4, inH = (tok >> 2) & 3, inW = tok & 3;
      int s = (wS * 4 + inS + SHIFT) & 31;
      int hh = (wH * 4 + inH + SHIFT) & 31;
      int ww = (wW * 4 + inW + SHIFT) & 31;
      size_t base = ((size_t)bI * 32768 + ((size_t)s * 32 + hh) * 32 + ww) * 192;
      float sum = 0.f, sq = 0.f;
#pragma unroll
      for (int n = 0; n < 2; n++) {
        int col = wv * 32 + n * 16 + c;
        float v = pacc[m][n][r] + proj_b[col];
        po[base + col] = f2bf(v);
        float y = v + x[base + col];
        yv[m][n][r] = y;
        sum += y; sq += y * y;
      }
#pragma unroll
      for (int mm = 1; mm < 16; mm <<= 1) { sum += __shfl_xor(sum, mm, 64); sq += __shfl_xor(sq, mm, 64); }
      if (c == 0) { pf[tok * 16 + wv] = sum; pf[tok * 16 + 8 + wv] = sq; }
    }
  __syncthreads();
#pragma unroll
  for (int m = 0; m < 4; m++)
#pragma unroll
    for (int r = 0; r < 4; r++) {
      int tok = m * 16 + g * 4 + r;
      int inS = tok >> 4, inH = (tok >> 2) & 3, inW = tok & 3;
      int s = (wS * 4 + inS + SHIFT) & 31;
      int hh = (wH * 4 + inH + SHIFT) & 31;
      int ww = (wW * 4 + inW + SHIFT) & 31;
      size_t base = ((size_t)bI * 32768 + ((size_t)s * 32 + hh) * 32 + ww) * 192;
      float su = 0.f, qu = 0.f;
#pragma unroll
      for (int w6 = 0; w6 < 6; w6++) { su += pf[tok * 16 + w6]; qu += pf[tok * 16 + 8 + w6]; }
      float mu = su * (1.f / 192.f);
      float rs = rsqrtf(qu * (1.f / 192.f) - mu * mu + 1e-5f);
#pragma unroll
      for (int n = 0; n < 2; n++) {
        int col = wv * 32 + n * 16 + c;
        hn[base + col] = f2bf((yv[m][n][r] - mu) * rs * g2[col] + b2[col]);
      }
    }
}

// ---------------- K4: fused fc1 + gelu + fc2 + residual -----------------------
// 1 block = 64 rows; h1 (64x768) lives in LDS; weights streamed from L2.
__global__ __launch_bounds__(384) void k_mlp(
    const u16* __restrict__ hn, const u16* __restrict__ f1T,
    const u16* __restrict__ f2T, const float* __restrict__ b1,
    const float* __restrict__ b2f, const float* __restrict__ x,
    const u16* __restrict__ po, float* __restrict__ out) {
  __shared__ u16 lhn[64 * 200];
  __shared__ u16 lh1[64 * 776];
  int blk = blockIdx.x;
  int tid = threadIdx.x, l = tid & 63, wv = tid >> 6, g = l >> 4, c = l & 15;
#pragma unroll
  for (int i = 0; i < 4; i++) {
    int cid = tid + i * 384;
    int row = cid / 24, ch = cid % 24;
    *(u16x8*)&lhn[row * 200 + ch * 8] =
        *(const u16x8*)&hn[((size_t)blk * 64 + row) * 192 + ch * 8];
  }
  __syncthreads();
  // phase 1: h1 cols wv*128..+127
  f32x4 acc1[4][8] = {};
#pragma unroll
  for (int ks = 0; ks < 6; ks++) {
    bf16x8 a1[4];
#pragma unroll
    for (int m = 0; m < 4; m++)
      a1[m] = *(const bf16x8*)&lhn[(m * 16 + c) * 200 + ks * 32 + g * 8];
#pragma unroll
    for (int n = 0; n < 8; n++) {
      bf16x8 b = *(const bf16x8*)&f1T[(size_t)(wv * 128 + n * 16 + c) * 192 + ks * 32 + g * 8];
#pragma unroll
      for (int m = 0; m < 4; m++) acc1[m][n] = mfma16(a1[m], b, acc1[m][n]);
    }
  }
#pragma unroll
  for (int m = 0; m < 4; m++)
#pragma unroll
    for (int n = 0; n < 8; n++) {
      int col = wv * 128 + n * 16 + c;
      float bias = b1[col];
#pragma unroll
      for (int r = 0; r < 4; r++) {
        float v = acc1[m][n][r] + bias;
        // gelu, tanh form: v * sigmoid(1.5957691*v + 0.07135481*v^3)
        float u2 = v * (1.5957691216f + 0.0713548163f * v * v);
        v = v * (1.f / (1.f + __expf(-u2)));
        lh1[(m * 16 + g * 4 + r) * 776 + col] = f2bf(v);
      }
    }
  __syncthreads();
  // phase 2: out cols wv*32..+31, K=768
  f32x4 acc2[4][2] = {};
  for (int ks = 0; ks < 24; ks++) {
    bf16x8 a2[4];
#pragma unroll
    for (int m = 0; m < 4; m++)
      a2[m] = *(const bf16x8*)&lh1[(m * 16 + c) * 776 + ks * 32 + g * 8];
#pragma unroll
    for (int n = 0; n < 2; n++) {
      bf16x8 b = *(const bf16x8*)&f2T[(size_t)(wv * 32 + n * 16 + c) * 768 + ks * 32 + g * 8];
#pragma unroll
      for (int m = 0; m < 4; m++) acc2[m][n] = mfma16(a2[m], b, acc2[m][n]);
    }
  }
#pragma unroll
  for (int m = 0; m < 4; m++)
#pragma unroll
    for (int n = 0; n < 2; n++)
#pragma unroll
      for (int r = 0; r < 4; r++) {
        int row = blk * 64 + m * 16 + g * 4 + r;
        int col = wv * 32 + n * 16 + c;
        size_t base = (size_t)row * 192 + col;
        out[base] = acc2[m][n][r] + b2f[col] + x[base] + bf2f(po[base]);
      }
}

extern "C" void kernel_launch(void* const* d_in, const int* in_sizes, int n_in,
                              void* d_out, int out_size, void* d_ws, size_t ws_size,
                              hipStream_t stream) {
  const float* x      = (const float*)d_in[0];
  const float* mask   = (const float*)d_in[1];
  const float* skip   = (const float*)d_in[2];
  const float* x_up   = (const float*)d_in[3];
  const float* n1g    = (const float*)d_in[4];
  const float* n1b    = (const float*)d_in[5];
  const float* kv_w   = (const float*)d_in[6];
  const float* kv_b   = (const float*)d_in[7];
  const float* rpb    = (const float*)d_in[8];
  const float* proj_w = (const float*)d_in[9];
  const float* proj_b = (const float*)d_in[10];
  const float* n2g    = (const float*)d_in[11];
  const float* n2b    = (const float*)d_in[12];
  const float* fc1_w  = (const float*)d_in[13];
  const float* fc1_b  = (const float*)d_in[14];
  const float* fc2_w  = (const float*)d_in[15];
  const float* fc2_b  = (const float*)d_in[16];
  char* ws = (char*)d_ws;
  u16* kvT  = (u16*)(ws + OFF_KVWT);
  u16* prT  = (u16*)(ws + OFF_PRWT);
  u16* f1T  = (u16*)(ws + OFF_FC1WT);
  u16* f2T  = (u16*)(ws + OFF_FC2WT);
  u16* skw  = (u16*)(ws + OFF_SKW);
  u16* qw   = (u16*)(ws + OFF_QW);
  u16* kvb  = (u16*)(ws + OFF_KVB);
  u16* hn   = (u16*)(ws + OFF_HN);
  u16* po   = (u16*)(ws + OFF_PO);
  float* out = (float*)d_out;

  k_prep<<<dim3(576), dim3(256), 0, stream>>>(kv_w, proj_w, fc1_w, fc2_w, kvT, prT, f1T, f2T);
  k_ln_part<<<dim3(16384), dim3(256), 0, stream>>>(skip, x_up, n1g, n1b, skw, qw);
  k_kv<<<dim3(512, 3), dim3(256), 0, stream>>>(skw, kvT, kv_b, kvb);
  k_attn_mega<<<dim3(1024), dim3(384), 0, stream>>>(
      qw, kvb, rpb, mask, prT, proj_b, x, n2g, n2b, hn, po);
  k_mlp<<<dim3(1024), dim3(384), 0, stream>>>(hn, f1T, f2T, fc1_b, fc2_b, x, po, out);
}

// Round 4
// 309.295 us; speedup vs baseline: 1.1766x; 1.0036x over previous
//
#include <hip/hip_runtime.h>
#include <math.h>

typedef unsigned short u16;
typedef __bf16 bf16x8 __attribute__((ext_vector_type(8)));
typedef float f32x4 __attribute__((ext_vector_type(4)));
typedef unsigned short u16x8 __attribute__((ext_vector_type(8)));

#define SHIFT 2

static __device__ __forceinline__ f32x4 mfma16(bf16x8 a, bf16x8 b, f32x4 c) {
  return __builtin_amdgcn_mfma_f32_16x16x32_bf16(a, b, c, 0, 0, 0);
}
static __device__ __forceinline__ u16 f2bf(float f) {
  unsigned u = __builtin_bit_cast(unsigned, f);
  unsigned r = u + 0x7fffu + ((u >> 16) & 1u);
  return (u16)(r >> 16);
}
static __device__ __forceinline__ float bf2f(u16 u) {
  unsigned v = (unsigned)u << 16;
  return __builtin_bit_cast(float, v);
}
static __device__ __forceinline__ void stage16(const u16* g, u16* lbase, int lane) {
#if __has_builtin(__builtin_amdgcn_global_load_lds)
  __builtin_amdgcn_global_load_lds(
      (const __attribute__((address_space(1))) unsigned int*)g,
      (__attribute__((address_space(3))) unsigned int*)lbase, 16, 0, 0);
#else
  *(u16x8*)(lbase + lane * 8) = *(const u16x8*)g;
#endif
}

// ---------------- workspace layout (bytes) ----------------
#define OFF_KVWT  ((size_t)0)                          // 384x192 bf16
#define OFF_PRWT  (OFF_KVWT + 384*192*2)               // 192x192
#define OFF_FC1WT (OFF_PRWT + 192*192*2)               // 768x192
#define OFF_FC2WT (OFF_FC1WT + 768*192*2)              // 192x768
#define OFF_SKW   (OFF_FC2WT + 192*768*2)              // 65536x192 bf16 (window order)
#define OFF_QW    (OFF_SKW + (size_t)65536*192*2)
#define OFF_KVB   (OFF_QW + (size_t)65536*192*2)       // 65536x384 bf16 (window order)
#define OFF_HN    (OFF_KVB + (size_t)65536*384*2)      // 65536x192 bf16 (natural)
#define OFF_PO    (OFF_HN + (size_t)65536*192*2)       // 65536x192 bf16 (natural)
// total = OFF_PO + 65536*192*2 = 151,805,952 B

// ---------------- K0: weight transpose + f32->bf16 ----------------
__global__ __launch_bounds__(256) void k_prep(
    const float* __restrict__ kv_w, const float* __restrict__ proj_w,
    const float* __restrict__ fc1_w, const float* __restrict__ fc2_w,
    u16* __restrict__ kvT, u16* __restrict__ prT,
    u16* __restrict__ f1T, u16* __restrict__ f2T) {
  int i = blockIdx.x * 256 + threadIdx.x;
  if (i < 192 * 384) kvT[(i % 384) * 192 + i / 384] = f2bf(kv_w[i]);
  if (i < 192 * 192) prT[(i % 192) * 192 + i / 192] = f2bf(proj_w[i]);
  if (i < 192 * 768) f1T[(i % 768) * 192 + i / 768] = f2bf(fc1_w[i]);
  if (i < 768 * 192) f2T[(i % 192) * 768 + i / 192] = f2bf(fc2_w[i]);
}

// ---------------- K1: LN + cyclic shift + window partition ----------------
__global__ __launch_bounds__(256) void k_ln_part(
    const float* __restrict__ skip, const float* __restrict__ x_up,
    const float* __restrict__ gam, const float* __restrict__ bet,
    u16* __restrict__ skw, u16* __restrict__ qw) {
  int row = blockIdx.x * 4 + (threadIdx.x >> 6);
  int lane = threadIdx.x & 63;
  const float* sp = skip + (size_t)row * 192;
  const float* qp = x_up + (size_t)row * 192;
  float sv[3], qv[3], ss = 0.f, qs = 0.f;
#pragma unroll
  for (int j = 0; j < 3; j++) {
    sv[j] = sp[lane + 64 * j]; qv[j] = qp[lane + 64 * j];
    ss += sv[j]; qs += qv[j];
  }
#pragma unroll
  for (int m = 1; m < 64; m <<= 1) { ss += __shfl_xor(ss, m, 64); qs += __shfl_xor(qs, m, 64); }
  float sm = ss * (1.f / 192.f), qm = qs * (1.f / 192.f);
  float s2 = 0.f, q2 = 0.f;
#pragma unroll
  for (int j = 0; j < 3; j++) { float d = sv[j] - sm; s2 += d * d; d = qv[j] - qm; q2 += d * d; }
#pragma unroll
  for (int m = 1; m < 64; m <<= 1) { s2 += __shfl_xor(s2, m, 64); q2 += __shfl_xor(q2, m, 64); }
  float sr = rsqrtf(s2 * (1.f / 192.f) + 1e-5f), qr = rsqrtf(q2 * (1.f / 192.f) + 1e-5f);
  int b = row >> 15, l = row & 32767;
  int s = l >> 10, h = (l >> 5) & 31, w = l & 31;
  int s_ = (s - SHIFT) & 31, h_ = (h - SHIFT) & 31, w_ = (w - SHIFT) & 31;
  int wIdx = ((s_ >> 2) * 8 + (h_ >> 2)) * 8 + (w_ >> 2);
  int n = ((s_ & 3) * 4 + (h_ & 3)) * 4 + (w_ & 3);
  size_t orow = ((size_t)(b * 512 + wIdx) * 64 + n) * 192;
  const float scale = 0.17677669529663687f;  // 32^-0.5
#pragma unroll
  for (int j = 0; j < 3; j++) {
    int cc = lane + 64 * j;
    float gg = gam[cc], bb = bet[cc];
    skw[orow + cc] = f2bf((sv[j] - sm) * sr * gg + bb);
    qw[orow + cc]  = f2bf(((qv[j] - qm) * qr * gg + bb) * scale);
  }
}

// ---------------- K2: kv GEMM (unchanged m97-style control) ----------------
__global__ __launch_bounds__(256) void k_kv(
    const u16* __restrict__ A, const u16* __restrict__ BT,
    const float* __restrict__ bias, u16* __restrict__ outh) {
  __shared__ u16 lds[(128 + 128) * 64];
  int mb = blockIdx.x, nb = blockIdx.y;
  int tid = threadIdx.x, w = tid >> 6, l = tid & 63;
  int wr = w >> 1, wc = w & 1, g = l >> 4, c = l & 15;
  f32x4 acc[4][4] = {};
  for (int ks = 0; ks < 3; ks++) {
    if (ks) __syncthreads();
    int k0 = ks * 64;
#pragma unroll
    for (int i = 0; i < 4; i++) {
      int s = w * 4 + i;
      stage16(&A[(size_t)(mb * 128 + s * 8 + (l >> 3)) * 192 + k0 + (l & 7) * 8],
              &lds[s * 512], l);
      stage16(&BT[(size_t)(nb * 128 + s * 8 + (l >> 3)) * 192 + k0 + (l & 7) * 8],
              &lds[8192 + s * 512], l);
    }
    __syncthreads();
#pragma unroll
    for (int kk = 0; kk < 2; kk++) {
      bf16x8 a[4];
#pragma unroll
      for (int m = 0; m < 4; m++)
        a[m] = *(const bf16x8*)&lds[(wr * 64 + m * 16 + c) * 64 + kk * 32 + g * 8];
#pragma unroll
      for (int n = 0; n < 4; n++) {
        bf16x8 b = *(const bf16x8*)&lds[8192 + (wc * 64 + n * 16 + c) * 64 + kk * 32 + g * 8];
#pragma unroll
        for (int m = 0; m < 4; m++) acc[m][n] = mfma16(a[m], b, acc[m][n]);
      }
    }
  }
#pragma unroll
  for (int m = 0; m < 4; m++)
#pragma unroll
    for (int n = 0; n < 4; n++)
#pragma unroll
      for (int r = 0; r < 4; r++) {
        int row = mb * 128 + wr * 64 + m * 16 + g * 4 + r;
        int col = nb * 128 + wc * 64 + n * 16 + c;
        outh[(size_t)row * 384 + col] = f2bf(acc[m][n][r] + bias[col]);
      }
}

// ---------------- K3: fused attention + proj + residual + LN2 -----------------
__global__ __launch_bounds__(384) void k_attn_mega(
    const u16* __restrict__ qw, const u16* __restrict__ kvb,
    const float* __restrict__ rpb, const float* __restrict__ mask,
    const u16* __restrict__ prT, const float* __restrict__ proj_b,
    const float* __restrict__ x, const float* __restrict__ g2,
    const float* __restrict__ b2, u16* __restrict__ hn, u16* __restrict__ po) {
  __shared__ u16 lv[64 * 200];       // V tile (row-major, padded)
  __shared__ u16 lp[6][16 * 72];     // per-head P m-slice
  __shared__ u16 lo[64 * 200];       // attention output tile
  __shared__ float pf[64 * 16];      // LN partials
  int b_ = blockIdx.x, wIdx = b_ & 511;
  int tid = threadIdx.x, l = tid & 63, wv = tid >> 6, g = l >> 4, c = l & 15;
#pragma unroll
  for (int i = 0; i < 4; i++) {
    int cid = tid + i * 384;
    int row = cid / 24, ch = cid % 24;
    *(u16x8*)&lv[row * 200 + ch * 8] =
        *(const u16x8*)&kvb[((size_t)b_ * 64 + row) * 384 + 192 + ch * 8];
  }
  __syncthreads();
  int h = wv;
  bf16x8 qa[4], kb[4];
#pragma unroll
  for (int m = 0; m < 4; m++)
    qa[m] = *(const bf16x8*)&qw[((size_t)b_ * 64 + m * 16 + c) * 192 + h * 32 + g * 8];
#pragma unroll
  for (int n = 0; n < 4; n++)
    kb[n] = *(const bf16x8*)&kvb[((size_t)b_ * 64 + n * 16 + c) * 384 + h * 32 + g * 8];
  f32x4 acc[4][4] = {};
#pragma unroll
  for (int m = 0; m < 4; m++)
#pragma unroll
    for (int n = 0; n < 4; n++) acc[m][n] = mfma16(qa[m], kb[n], acc[m][n]);
  bf16x8 vb[2][2];
#pragma unroll
  for (int kk = 0; kk < 2; kk++)
#pragma unroll
    for (int nd = 0; nd < 2; nd++) {
      union { u16 u[8]; bf16x8 v; } bb;
#pragma unroll
      for (int j = 0; j < 8; j++)
        bb.u[j] = lv[(kk * 32 + g * 8 + j) * 200 + h * 32 + nd * 16 + c];
      vb[kk][nd] = bb.v;
    }
  const float* mrow = mask + (size_t)wIdx * 4096;
  f32x4 oacc[4][2] = {};
#pragma unroll
  for (int m = 0; m < 4; m++) {
#pragma unroll
    for (int r = 0; r < 4; r++) {
      int qr = m * 16 + g * 4 + r;
      int qs = qr >> 4, qh = (qr >> 2) & 3, qx = qr & 3;
      float vals[4];
#pragma unroll
      for (int n = 0; n < 4; n++) {
        int kc = n * 16 + c;
        int ks = kc >> 4, kh = (kc >> 2) & 3, kx = kc & 3;
        int idx = (qs - ks + 3) * 11 + (qh - kh + 3) * 7 + (qx - kx + 3);
        vals[n] = acc[m][n][r] + rpb[idx * 6 + h] + mrow[qr * 64 + kc];
      }
      float mx = fmaxf(fmaxf(vals[0], vals[1]), fmaxf(vals[2], vals[3]));
#pragma unroll
      for (int mm = 1; mm < 16; mm <<= 1) mx = fmaxf(mx, __shfl_xor(mx, mm, 64));
      float sum = 0.f;
#pragma unroll
      for (int n = 0; n < 4; n++) { vals[n] = __expf(vals[n] - mx); sum += vals[n]; }
#pragma unroll
      for (int mm = 1; mm < 16; mm <<= 1) sum += __shfl_xor(sum, mm, 64);
      float inv = 1.f / sum;
#pragma unroll
      for (int n = 0; n < 4; n++)
        lp[h][(g * 4 + r) * 72 + n * 16 + c] = f2bf(vals[n] * inv);
    }
#pragma unroll
    for (int kk = 0; kk < 2; kk++) {
      bf16x8 pa = *(const bf16x8*)&lp[h][c * 72 + kk * 32 + g * 8];
#pragma unroll
      for (int nd = 0; nd < 2; nd++) oacc[m][nd] = mfma16(pa, vb[kk][nd], oacc[m][nd]);
    }
  }
#pragma unroll
  for (int m = 0; m < 4; m++)
#pragma unroll
    for (int nd = 0; nd < 2; nd++)
#pragma unroll
      for (int r = 0; r < 4; r++)
        lo[(m * 16 + g * 4 + r) * 200 + h * 32 + nd * 16 + c] = f2bf(oacc[m][nd][r]);
  __syncthreads();
  f32x4 pacc[4][2] = {};
#pragma unroll
  for (int ks = 0; ks < 6; ks++) {
    bf16x8 pa[4];
#pragma unroll
    for (int m = 0; m < 4; m++)
      pa[m] = *(const bf16x8*)&lo[(m * 16 + c) * 200 + ks * 32 + g * 8];
#pragma unroll
    for (int n = 0; n < 2; n++) {
      bf16x8 pb = *(const bf16x8*)&prT[(size_t)(wv * 32 + n * 16 + c) * 192 + ks * 32 + g * 8];
#pragma unroll
      for (int m = 0; m < 4; m++) pacc[m][n] = mfma16(pa[m], pb, pacc[m][n]);
    }
  }
  int bI = b_ >> 9;
  int wS = wIdx >> 6, wH = (wIdx >> 3) & 7, wW = wIdx & 7;
  float yv[4][2][4];
#pragma unroll
  for (int m = 0; m < 4; m++)
#pragma unroll
    for (int r = 0; r < 4; r++) {
      int tok = m * 16 + g * 4 + r;
      int inS = tok >> 4, inH = (tok >> 2) & 3, inW = tok & 3;
      int s = (wS * 4 + inS + SHIFT) & 31;
      int hh = (wH * 4 + inH + SHIFT) & 31;
      int ww = (wW * 4 + inW + SHIFT) & 31;
      size_t base = ((size_t)bI * 32768 + ((size_t)s * 32 + hh) * 32 + ww) * 192;
      float sum = 0.f, sq = 0.f;
#pragma unroll
      for (int n = 0; n < 2; n++) {
        int col = wv * 32 + n * 16 + c;
        float v = pacc[m][n][r] + proj_b[col];
        po[base + col] = f2bf(v);
        float y = v + x[base + col];
        yv[m][n][r] = y;
        sum += y; sq += y * y;
      }
#pragma unroll
      for (int mm = 1; mm < 16; mm <<= 1) { sum += __shfl_xor(sum, mm, 64); sq += __shfl_xor(sq, mm, 64); }
      if (c == 0) { pf[tok * 16 + wv] = sum; pf[tok * 16 + 8 + wv] = sq; }
    }
  __syncthreads();
#pragma unroll
  for (int m = 0; m < 4; m++)
#pragma unroll
    for (int r = 0; r < 4; r++) {
      int tok = m * 16 + g * 4 + r;
      int inS = tok >> 4, inH = (tok >> 2) & 3, inW = tok & 3;
      int s = (wS * 4 + inS + SHIFT) & 31;
      int hh = (wH * 4 + inH + SHIFT) & 31;
      int ww = (wW * 4 + inW + SHIFT) & 31;
      size_t base = ((size_t)bI * 32768 + ((size_t)s * 32 + hh) * 32 + ww) * 192;
      float su = 0.f, qu = 0.f;
#pragma unroll
      for (int w6 = 0; w6 < 6; w6++) { su += pf[tok * 16 + w6]; qu += pf[tok * 16 + 8 + w6]; }
      float mu = su * (1.f / 192.f);
      float rs = rsqrtf(qu * (1.f / 192.f) - mu * mu + 1e-5f);
#pragma unroll
      for (int n = 0; n < 2; n++) {
        int col = wv * 32 + n * 16 + c;
        hn[base + col] = f2bf((yv[m][n][r] - mu) * rs * g2[col] + b2[col]);
      }
    }
}

// ---------------- K4: fused fc1+gelu+fc2, K-chunked (h1 never materialized) ----
// 1 block = 64 rows, 6 waves; each wave owns a 32-col strip of the 192-col
// output AND of each 192-col h1 chunk. LDS = lhn + one h1 chunk = 51 KB
// (vs 122 KB monolithic, which capped occupancy at 1 block/CU last round).
__global__ __launch_bounds__(384, 3) void k_mlp(
    const u16* __restrict__ hn, const u16* __restrict__ f1T,
    const u16* __restrict__ f2T, const float* __restrict__ b1,
    const float* __restrict__ b2f, const float* __restrict__ x,
    const u16* __restrict__ po, float* __restrict__ out) {
  __shared__ u16 lhn[64 * 200];
  __shared__ u16 lh1c[64 * 200];
  int blk = blockIdx.x;
  int tid = threadIdx.x, l = tid & 63, wv = tid >> 6, g = l >> 4, c = l & 15;
#pragma unroll
  for (int i = 0; i < 4; i++) {
    int cid = tid + i * 384;
    int row = cid / 24, ch = cid % 24;
    *(u16x8*)&lhn[row * 200 + ch * 8] =
        *(const u16x8*)&hn[((size_t)blk * 64 + row) * 192 + ch * 8];
  }
  __syncthreads();
  f32x4 acc2[4][2] = {};
#pragma unroll 1
  for (int ko = 0; ko < 4; ko++) {
    // fc1 chunk: h1 cols ko*192 + wv*32 .. +31 (reads only lhn + f1T: no hazard)
    f32x4 acc1[4][2] = {};
#pragma unroll
    for (int ks = 0; ks < 6; ks++) {
      bf16x8 a1[4];
#pragma unroll
      for (int m = 0; m < 4; m++)
        a1[m] = *(const bf16x8*)&lhn[(m * 16 + c) * 200 + ks * 32 + g * 8];
#pragma unroll
      for (int n = 0; n < 2; n++) {
        bf16x8 b = *(const bf16x8*)&f1T[(size_t)(ko * 192 + wv * 32 + n * 16 + c) * 192 + ks * 32 + g * 8];
#pragma unroll
        for (int m = 0; m < 4; m++) acc1[m][n] = mfma16(a1[m], b, acc1[m][n]);
      }
    }
    if (ko) __syncthreads();  // prior chunk's fc2 reads must finish before overwrite
#pragma unroll
    for (int m = 0; m < 4; m++)
#pragma unroll
      for (int n = 0; n < 2; n++) {
        int col = ko * 192 + wv * 32 + n * 16 + c;
        float bias = b1[col];
#pragma unroll
        for (int r = 0; r < 4; r++) {
          float v = acc1[m][n][r] + bias;
          float u2 = v * (1.5957691216f + 0.0713548163f * v * v);
          v = v * (1.f / (1.f + __expf(-u2)));
          lh1c[(m * 16 + g * 4 + r) * 200 + wv * 32 + n * 16 + c] = f2bf(v);
        }
      }
    __syncthreads();
    // fc2 chunk: accumulate K = ko*192 .. +191
#pragma unroll
    for (int ks = 0; ks < 6; ks++) {
      bf16x8 a2[4];
#pragma unroll
      for (int m = 0; m < 4; m++)
        a2[m] = *(const bf16x8*)&lh1c[(m * 16 + c) * 200 + ks * 32 + g * 8];
#pragma unroll
      for (int n = 0; n < 2; n++) {
        bf16x8 b = *(const bf16x8*)&f2T[(size_t)(wv * 32 + n * 16 + c) * 768 + ko * 192 + ks * 32 + g * 8];
#pragma unroll
        for (int m = 0; m < 4; m++) acc2[m][n] = mfma16(a2[m], b, acc2[m][n]);
      }
    }
  }
#pragma unroll
  for (int m = 0; m < 4; m++)
#pragma unroll
    for (int n = 0; n < 2; n++)
#pragma unroll
      for (int r = 0; r < 4; r++) {
        int row = blk * 64 + m * 16 + g * 4 + r;
        int col = wv * 32 + n * 16 + c;
        size_t base = (size_t)row * 192 + col;
        out[base] = acc2[m][n][r] + b2f[col] + x[base] + bf2f(po[base]);
      }
}

extern "C" void kernel_launch(void* const* d_in, const int* in_sizes, int n_in,
                              void* d_out, int out_size, void* d_ws, size_t ws_size,
                              hipStream_t stream) {
  const float* x      = (const float*)d_in[0];
  const float* mask   = (const float*)d_in[1];
  const float* skip   = (const float*)d_in[2];
  const float* x_up   = (const float*)d_in[3];
  const float* n1g    = (const float*)d_in[4];
  const float* n1b    = (const float*)d_in[5];
  const float* kv_w   = (const float*)d_in[6];
  const float* kv_b   = (const float*)d_in[7];
  const float* rpb    = (const float*)d_in[8];
  const float* proj_w = (const float*)d_in[9];
  const float* proj_b = (const float*)d_in[10];
  const float* n2g    = (const float*)d_in[11];
  const float* n2b    = (const float*)d_in[12];
  const float* fc1_w  = (const float*)d_in[13];
  const float* fc1_b  = (const float*)d_in[14];
  const float* fc2_w  = (const float*)d_in[15];
  const float* fc2_b  = (const float*)d_in[16];
  char* ws = (char*)d_ws;
  u16* kvT  = (u16*)(ws + OFF_KVWT);
  u16* prT  = (u16*)(ws + OFF_PRWT);
  u16* f1T  = (u16*)(ws + OFF_FC1WT);
  u16* f2T  = (u16*)(ws + OFF_FC2WT);
  u16* skw  = (u16*)(ws + OFF_SKW);
  u16* qw   = (u16*)(ws + OFF_QW);
  u16* kvb  = (u16*)(ws + OFF_KVB);
  u16* hn   = (u16*)(ws + OFF_HN);
  u16* po   = (u16*)(ws + OFF_PO);
  float* out = (float*)d_out;

  k_prep<<<dim3(576), dim3(256), 0, stream>>>(kv_w, proj_w, fc1_w, fc2_w, kvT, prT, f1T, f2T);
  k_ln_part<<<dim3(16384), dim3(256), 0, stream>>>(skip, x_up, n1g, n1b, skw, qw);
  k_kv<<<dim3(512, 3), dim3(256), 0, stream>>>(skw, kvT, kv_b, kvb);
  k_attn_mega<<<dim3(1024), dim3(384), 0, stream>>>(
      qw, kvb, rpb, mask, prT, proj_b, x, n2g, n2b, hn, po);
  k_mlp<<<dim3(1024), dim3(384), 0, stream>>>(hn, f1T, f2T, fc1_b, fc2_b, x, po, out);
}